// Round 6
// baseline (422.729 us; speedup 1.0000x reference)
//
#include <hip/hip_runtime.h>
#include <hip/hip_bf16.h>

#define DD 128
#define RR 8
#define KK 1152      // RGCN composite K = 128 + 8*128
#define SCAN_CHUNK 2048
#define KSPLIT 8
#define KP 4096      // padded sim K

typedef _Float16 h8 __attribute__((ext_vector_type(8)));
typedef _Float16 h4 __attribute__((ext_vector_type(4)));
typedef float f4 __attribute__((ext_vector_type(4)));

__device__ __forceinline__ void gload16(const _Float16* g, _Float16* l) {
  __builtin_amdgcn_global_load_lds(
      (const __attribute__((address_space(1))) void*)g,
      (__attribute__((address_space(3))) void*)l, 16, 0, 0);
}

// ---------------- count edges per (dst, rel) and in-degree ----------------
__global__ __launch_bounds__(256) void count_k(const int* __restrict__ edst,
    const int* __restrict__ etyp, int* __restrict__ cnt, int* __restrict__ deg, int E) {
  int i = blockIdx.x * 256 + threadIdx.x;
  if (i < E) {
    int d = edst[i];
    atomicAdd(&cnt[d * RR + etyp[i]], 1);
    atomicAdd(&deg[d], 1);
  }
}

// ---------------- 3-phase exclusive scan of cnt -> off ----------------
__global__ __launch_bounds__(256) void scan_a(const int* __restrict__ cnt,
    int* __restrict__ off, int* __restrict__ bsum, int n) {
  __shared__ int red[256];
  int base = blockIdx.x * SCAN_CHUNK + threadIdx.x * 8;
  int v[8];
  int s = 0;
#pragma unroll
  for (int i = 0; i < 8; ++i) {
    int idx = base + i;
    v[i] = s;
    s += (idx < n) ? cnt[idx] : 0;
  }
  red[threadIdx.x] = s;
  __syncthreads();
  for (int o = 1; o < 256; o <<= 1) {
    int t = (threadIdx.x >= o) ? red[threadIdx.x - o] : 0;
    __syncthreads();
    red[threadIdx.x] += t;
    __syncthreads();
  }
  int pre = (threadIdx.x > 0) ? red[threadIdx.x - 1] : 0;
#pragma unroll
  for (int i = 0; i < 8; ++i) {
    int idx = base + i;
    if (idx < n) off[idx] = v[i] + pre;
  }
  if (threadIdx.x == 255) bsum[blockIdx.x] = red[255];
}

__global__ void scan_b(int* __restrict__ bsum, int nb) {
  if (threadIdx.x == 0) {
    int s = 0;
    for (int i = 0; i < nb; ++i) { int t = bsum[i]; bsum[i] = s; s += t; }
  }
}

__global__ __launch_bounds__(256) void scan_c(int* __restrict__ off,
    const int* __restrict__ bsum, int n) {
  int i = blockIdx.x * 256 + threadIdx.x;
  if (i < n) off[i] += bsum[i >> 11];
}

// ---------------- fill CSR ----------------
__global__ __launch_bounds__(256) void fill_k(const int* __restrict__ esrc,
    const int* __restrict__ edst, const int* __restrict__ etyp,
    int* __restrict__ cur, int* __restrict__ eidx, int E) {
  int e = blockIdx.x * 256 + threadIdx.x;
  if (e < E) {
    int seg = edst[e] * RR + etyp[e];
    int p = atomicAdd(&cur[seg], 1);
    eidx[p] = esrc[e];
  }
}

// ---------------- fp32 -> f16 convert of x ----------------
__global__ __launch_bounds__(256) void convx_k(const float* __restrict__ x,
    _Float16* __restrict__ xh, int n4) {
  int i = blockIdx.x * 256 + threadIdx.x;
  if (i < n4) {
    float4 v = *(const float4*)(x + (size_t)i * 4);
    h4 o = {(_Float16)v.x, (_Float16)v.y, (_Float16)v.z, (_Float16)v.w};
    *(h4*)(xh + (size_t)i * 4) = o;
  }
}

// ---------------- build transposed f16 weights WT[n][k] ----------------
__global__ __launch_bounds__(256) void convw_k(const float* __restrict__ Ws,
    const float* __restrict__ Wr, _Float16* __restrict__ WT) {
  int gid = blockIdx.x * 256 + threadIdx.x;
  if (gid < DD * KK) {
    int n = gid / KK, k = gid % KK;
    float v = (k < DD) ? Ws[(size_t)k * DD + n] : Wr[(size_t)(k - DD) * DD + n];
    WT[gid] = (_Float16)v;
  }
}

// ---------------- FUSED RGCN layer, barrier-free wave-split-K ----------------
// Block: 256 thr = 4 waves, 16 output rows. Wave w handles: self k-window
// [w*32, w*32+32) + relations {2w, 2w+1}. Gather -> A-fragment in registers
// (lane: row=lane&15, k-part=lane>>4). B fragments read directly from WT
// (L2-resident). No barriers in the K-path; one LDS reduce at the end.
template <bool RELU, bool F16OUT>
__global__ __launch_bounds__(256, 3) void rgcn_fused(const _Float16* __restrict__ hfeat,
    const int* __restrict__ off, const int* __restrict__ eidx,
    const _Float16* __restrict__ WT, void* __restrict__ outv, int nN, int E) {
  __shared__ float red[4][16 * 128];
  const int t = threadIdx.x;
  const int lane = t & 63, w = t >> 6;
  const int lr = lane & 15, part = lane >> 4;
  const int row0 = blockIdx.x * 16;
  const int row = row0 + lr;
  const int NRtot = nN * RR;

  f4 acc[8];
#pragma unroll
  for (int ni = 0; ni < 8; ++ni) acc[ni] = (f4){0.f, 0.f, 0.f, 0.f};

  // ---- self sub-step: k-window [w*32, w*32+32) ----
  {
    const int kb = w * 32 + part * 8;
    h8 af = *(const h8*)(hfeat + (size_t)row * DD + kb);
#pragma unroll
    for (int ni = 0; ni < 8; ++ni) {
      h8 bf = *(const h8*)(WT + (size_t)(ni * 16 + lr) * KK + kb);
      acc[ni] = __builtin_amdgcn_mfma_f32_16x16x32_f16(af, bf, acc[ni], 0, 0, 0);
    }
  }

  // ---- two relations per wave ----
#pragma unroll
  for (int rsel = 0; rsel < 2; ++rsel) {
    const int r = w * 2 + rsel;
    const int seg = row * RR + r;
    const int b = off[seg];
    const int e = (seg + 1 < NRtot) ? off[seg + 1] : E;
    float a[32];
#pragma unroll
    for (int j = 0; j < 32; ++j) a[j] = 0.f;
    for (int i = b; i < e; ++i) {
      const _Float16* hp = hfeat + (size_t)eidx[i] * DD + part * 8;
      h8 v0 = *(const h8*)hp;
      h8 v1 = *(const h8*)(hp + 32);
      h8 v2 = *(const h8*)(hp + 64);
      h8 v3 = *(const h8*)(hp + 96);
#pragma unroll
      for (int j = 0; j < 8; ++j) {
        a[j]      += (float)v0[j];
        a[8 + j]  += (float)v1[j];
        a[16 + j] += (float)v2[j];
        a[24 + j] += (float)v3[j];
      }
    }
    const float ic = (e > b) ? 1.0f / (float)(e - b) : 0.0f;
    h8 af[4];
#pragma unroll
    for (int s = 0; s < 4; ++s)
#pragma unroll
      for (int j = 0; j < 8; ++j) af[s][j] = (_Float16)(a[s * 8 + j] * ic);

    const int kb0 = DD + r * DD + part * 8;
#pragma unroll
    for (int s = 0; s < 4; ++s) {
      const int kb = kb0 + s * 32;
#pragma unroll
      for (int ni = 0; ni < 8; ++ni) {
        h8 bf = *(const h8*)(WT + (size_t)(ni * 16 + lr) * KK + kb);
        acc[ni] = __builtin_amdgcn_mfma_f32_16x16x32_f16(af[s], bf, acc[ni], 0, 0, 0);
      }
    }
  }

  // ---- block reduction over the 4 K-partitions ----
  // D-frag: row_in_tile = part*4 + j, col = ni*16 + lr
#pragma unroll
  for (int ni = 0; ni < 8; ++ni)
#pragma unroll
    for (int j = 0; j < 4; ++j)
      red[w][(part * 4 + j) * 128 + ni * 16 + lr] = acc[ni][j];
  __syncthreads();

  const int base = t * 8;  // 16*128 / 256 threads = 8 elems each
  const int orow = base >> 7, ocol = base & 127;
  f4 s0 = (f4){0.f, 0.f, 0.f, 0.f}, s1 = s0;
#pragma unroll
  for (int ww = 0; ww < 4; ++ww) {
    const float* p = &red[ww][orow * 128 + ocol];
    s0 += *(const f4*)p;
    s1 += *(const f4*)(p + 4);
  }
  if (RELU) {
#pragma unroll
    for (int j = 0; j < 4; ++j) {
      s0[j] = fmaxf(s0[j], 0.f);
      s1[j] = fmaxf(s1[j], 0.f);
    }
  }
  const int grow = row0 + orow;
  if (grow < nN) {
    if (F16OUT) {
      h8 o;
#pragma unroll
      for (int j = 0; j < 4; ++j) { o[j] = (_Float16)s0[j]; o[4 + j] = (_Float16)s1[j]; }
      *(h8*)((_Float16*)outv + (size_t)grow * DD + ocol) = o;
    } else {
      float* po = (float*)outv + (size_t)grow * DD + ocol;
      *(f4*)po = s0;
      *(f4*)(po + 4) = s1;
    }
  }
}

// ---------------- maskf scatter: maskf[mri[i]] = 1 ----------------
__global__ __launch_bounds__(256) void maskset_k(const int* __restrict__ mri,
    float* __restrict__ maskf, int nd) {
  int i = blockIdx.x * 256 + threadIdx.x;
  if (i < nd) maskf[mri[i]] = 1.0f;
}

// ---------------- sim row convert + fused rowsum ----------------
__global__ __launch_bounds__(256) void convsim_k(const float* __restrict__ sim,
    const int* __restrict__ mri, const float* __restrict__ maskf,
    _Float16* __restrict__ simh, float* __restrict__ rs, int nd) {
  __shared__ float red[256];
  int i = blockIdx.x;
  const float* row = sim + (size_t)mri[i] * nd;
  float acc = 0.f;
  for (int c4 = threadIdx.x; c4 < KP / 4; c4 += 256) {
    int c = c4 * 4;
    float4 v = make_float4(0.f, 0.f, 0.f, 0.f);
    if (c < nd) {
      v = *(const float4*)(row + c);
      float4 mk = *(const float4*)(maskf + c);
      acc += v.x * mk.x + v.y * mk.y + v.z * mk.z + v.w * mk.w;
    }
    h4 o = {(_Float16)v.x, (_Float16)v.y, (_Float16)v.z, (_Float16)v.w};
    *(h4*)(simh + (size_t)i * KP + c) = o;
  }
  red[threadIdx.x] = acc;
  __syncthreads();
  for (int o = 128; o > 0; o >>= 1) {
    if (threadIdx.x < o) red[threadIdx.x] += red[threadIdx.x + o];
    __syncthreads();
  }
  if (threadIdx.x == 0) rs[i] = red[0] + 1e-9f;
}

// ---------------- gather disease rows (fp32 hbp) + scatter f16 into hbs ----------------
__global__ __launch_bounds__(256) void gather2_k(const float* __restrict__ h2,
    const int* __restrict__ bli, const int* __restrict__ mri,
    float* __restrict__ hbp, _Float16* __restrict__ hbs, int nd) {
  int gid = blockIdx.x * 256 + threadIdx.x;
  int i = gid >> 5, q = gid & 31;
  if (i < nd) {
    float4 v = *(const float4*)(h2 + (size_t)bli[i] * DD + q * 4);
    *(float4*)(hbp + (size_t)i * DD + q * 4) = v;
    h4 o = {(_Float16)v.x, (_Float16)v.y, (_Float16)v.z, (_Float16)v.w};
    *(h4*)(hbs + (size_t)mri[i] * DD + q * 4) = o;
  }
}

// ---------------- transpose hbs[KP][128] -> hbsT[128][KP] ----------------
__global__ __launch_bounds__(256) void transpose_k(const _Float16* __restrict__ hbs,
    _Float16* __restrict__ hbsT) {
  __shared__ _Float16 tile[64][72];
  int r0 = blockIdx.x * 64, c0 = blockIdx.y * 64;
  int t = threadIdx.x;
  int r = t >> 2, cs = (t & 3) * 16;
  *(h8*)&tile[r][cs]     = *(const h8*)(hbs + (size_t)(r0 + r) * DD + c0 + cs);
  *(h8*)&tile[r][cs + 8] = *(const h8*)(hbs + (size_t)(r0 + r) * DD + c0 + cs + 8);
  __syncthreads();
  int n = t >> 2, rs2 = (t & 3) * 16;
  h8 o0, o1;
#pragma unroll
  for (int j = 0; j < 8; ++j) {
    o0[j] = tile[rs2 + j][n];
    o1[j] = tile[rs2 + 8 + j][n];
  }
  *(h8*)(hbsT + (size_t)(c0 + n) * KP + r0 + rs2)     = o0;
  *(h8*)(hbsT + (size_t)(c0 + n) * KP + r0 + rs2 + 8) = o1;
}

// ---------------- sim MFMA GEMM: hs_part[ky] = simh[:, kchunk] @ hbsT^T ----------------
__global__ __launch_bounds__(256) void sim_mfma(const _Float16* __restrict__ simh,
    const _Float16* __restrict__ hbsT, float* __restrict__ hs_part, int nd) {
  __shared__ _Float16 Ab[2][64 * 64];
  __shared__ _Float16 Bb[2][128 * 64];
  const int t = threadIdx.x;
  const int lane = t & 63, w = t >> 6;
  const int row0 = blockIdx.x * 64;
  const int kb0 = blockIdx.y * (KP / KSPLIT);
  const int wm = w >> 1, wn = w & 1;
  const int lr = lane & 15, lg = lane >> 4;

  f4 acc[2][4];
#pragma unroll
  for (int mi = 0; mi < 2; ++mi)
#pragma unroll
    for (int ni = 0; ni < 4; ++ni) acc[mi][ni] = (f4){0.f, 0.f, 0.f, 0.f};

  const _Float16* pA[2];
  int ldsA[2];
#pragma unroll
  for (int j = 0; j < 2; ++j) {
    int q = j * 256 + w * 64 + lane;
    int row = q >> 3;
    int gck = (q & 7) ^ (row & 7);
    int m = row0 + row; if (m >= nd) m = nd - 1;
    pA[j] = simh + (size_t)m * KP + kb0 + gck * 8;
    ldsA[j] = (j * 256 + w * 64) * 8;
  }
  const _Float16* pB[4];
  int ldsB[4];
#pragma unroll
  for (int i = 0; i < 4; ++i) {
    int q = i * 256 + w * 64 + lane;
    int n = q >> 3;
    int gck = (q & 7) ^ (n & 7);
    pB[i] = hbsT + (size_t)n * KP + kb0 + gck * 8;
    ldsB[i] = (i * 256 + w * 64) * 8;
  }

  const int nsteps = (KP / KSPLIT) / 64;  // 8
#pragma unroll
  for (int j = 0; j < 2; ++j) gload16(pA[j], &Ab[0][ldsA[j]]);
#pragma unroll
  for (int i = 0; i < 4; ++i) gload16(pB[i], &Bb[0][ldsB[i]]);
  asm volatile("s_waitcnt vmcnt(0)" ::: "memory");
  __syncthreads();

  for (int ts = 0; ts < nsteps; ++ts) {
    const int cur = ts & 1;
    if (ts + 1 < nsteps) {
      const int kk = (ts + 1) * 64;
      const int nxt = cur ^ 1;
#pragma unroll
      for (int j = 0; j < 2; ++j) gload16(pA[j] + kk, &Ab[nxt][ldsA[j]]);
#pragma unroll
      for (int i = 0; i < 4; ++i) gload16(pB[i] + kk, &Bb[nxt][ldsB[i]]);
    }
#pragma unroll
    for (int s = 0; s < 2; ++s) {
      h8 af[2], bf[4];
#pragma unroll
      for (int mi = 0; mi < 2; ++mi) {
        int r = wm * 32 + mi * 16 + lr;
        af[mi] = *(const h8*)&Ab[cur][r * 64 + (((s * 4 + lg) ^ (r & 7)) << 3)];
      }
#pragma unroll
      for (int ni = 0; ni < 4; ++ni) {
        int n = wn * 64 + ni * 16 + lr;
        bf[ni] = *(const h8*)&Bb[cur][n * 64 + (((s * 4 + lg) ^ (n & 7)) << 3)];
      }
#pragma unroll
      for (int mi = 0; mi < 2; ++mi)
#pragma unroll
        for (int ni = 0; ni < 4; ++ni)
          acc[mi][ni] = __builtin_amdgcn_mfma_f32_16x16x32_f16(
              af[mi], bf[ni], acc[mi][ni], 0, 0, 0);
    }
    asm volatile("s_waitcnt vmcnt(0)" ::: "memory");
    __syncthreads();
  }

  float* dst = hs_part + (size_t)blockIdx.y * nd * DD;
#pragma unroll
  for (int mi = 0; mi < 2; ++mi) {
#pragma unroll
    for (int j = 0; j < 4; ++j) {
      int row = row0 + wm * 32 + mi * 16 + lg * 4 + j;
      if (row < nd) {
#pragma unroll
        for (int ni = 0; ni < 4; ++ni) {
          int col = wn * 64 + ni * 16 + lr;
          dst[(size_t)row * DD + col] = acc[mi][ni][j];
        }
      }
    }
  }
}

__global__ __launch_bounds__(256) void reduce_k(const float* __restrict__ part,
    float* __restrict__ hs, int n) {
  int i = blockIdx.x * 256 + threadIdx.x;
  if (i < n) {
    float4 s = make_float4(0.f, 0.f, 0.f, 0.f);
#pragma unroll
    for (int p = 0; p < KSPLIT; ++p) {
      float4 v = *(const float4*)(part + (size_t)p * n * 4 + i * 4);
      s.x += v.x; s.y += v.y; s.z += v.z; s.w += v.w;
    }
    *(float4*)(hs + (size_t)i * 4) = s;
  }
}

// ---------------- final blend into d_out at disease rows ----------------
__global__ __launch_bounds__(256) void final_k(const float* __restrict__ hs,
    const float* __restrict__ hbp, const float* __restrict__ rs,
    const int* __restrict__ bli, const int* __restrict__ deg,
    float* __restrict__ out, int nd) {
  int gid = blockIdx.x * 256 + threadIdx.x;
  int i = gid >> 5, q = gid & 31;
  if (i < nd) {
    int g = bli[i];
    float cg = 0.7f * expf(-0.7f * (float)deg[g]) + 0.2f;
    float inv = 1.0f / rs[i];
    float4 s = *(const float4*)(hs + (size_t)i * DD + q * 4);
    float4 b = *(const float4*)(hbp + (size_t)i * DD + q * 4);
    float4 o;
    o.x = cg * (s.x * inv) + (1.f - cg) * b.x;
    o.y = cg * (s.y * inv) + (1.f - cg) * b.y;
    o.z = cg * (s.z * inv) + (1.f - cg) * b.z;
    o.w = cg * (s.w * inv) + (1.f - cg) * b.w;
    *(float4*)(out + (size_t)g * DD + q * 4) = o;
  }
}

extern "C" void kernel_launch(void* const* d_in, const int* in_sizes, int n_in,
                              void* d_out, int out_size, void* d_ws, size_t ws_size,
                              hipStream_t stream) {
  const float* x   = (const float*)d_in[0];
  const float* sim = (const float*)d_in[1];
  const float* W1s = (const float*)d_in[2];
  const float* W1r = (const float*)d_in[3];
  const float* W2s = (const float*)d_in[4];
  const float* W2r = (const float*)d_in[5];
  const int* esrc  = (const int*)d_in[6];
  const int* edst  = (const int*)d_in[7];
  const int* etyp  = (const int*)d_in[8];
  const int* bli   = (const int*)d_in[9];
  const int* mri   = (const int*)d_in[10];
  const int N  = in_sizes[0] / DD;
  const int E  = in_sizes[6];
  const int ND = in_sizes[9];
  const int NR = N * RR;
  float* out = (float*)d_out;

  // workspace carve-up (~83 MB)
  char* w = (char*)d_ws;
  _Float16* xh   = (_Float16*)w; w += (size_t)N * DD * sizeof(_Float16);
  _Float16* h1h  = (_Float16*)w; w += (size_t)N * DD * sizeof(_Float16);
  _Float16* WT1  = (_Float16*)w; w += (size_t)DD * KK * sizeof(_Float16);
  _Float16* WT2  = (_Float16*)w; w += (size_t)DD * KK * sizeof(_Float16);
  _Float16* simh = (_Float16*)w; w += (size_t)ND * KP * sizeof(_Float16);
  _Float16* hbs  = (_Float16*)w; w += (size_t)KP * DD * sizeof(_Float16);
  _Float16* hbsT = (_Float16*)w; w += (size_t)DD * KP * sizeof(_Float16);
  float* hs_part = (float*)w; w += (size_t)KSPLIT * ND * DD * sizeof(float);
  float* hbp   = (float*)w; w += (size_t)ND * DD * sizeof(float);
  float* hs    = (float*)w; w += (size_t)ND * DD * sizeof(float);
  float* maskf = (float*)w; w += (size_t)KP * sizeof(float);
  int* cnt  = (int*)w; w += (size_t)NR * sizeof(int);
  int* deg  = (int*)w; w += (size_t)N * sizeof(int);
  int* off  = (int*)w; w += (size_t)NR * sizeof(int);
  int* cur  = (int*)w; w += (size_t)NR * sizeof(int);
  int* eidx = (int*)w; w += (size_t)E * sizeof(int);
  int* bsum = (int*)w; w += 1024 * sizeof(int);
  float* rs = (float*)w; w += (size_t)ND * sizeof(float);

  // ---- CSR build ----
  hipMemsetAsync(cnt, 0, (size_t)(NR + N) * sizeof(int), stream);
  count_k<<<(E + 255) / 256, 256, 0, stream>>>(edst, etyp, cnt, deg, E);
  int nblk = (NR + SCAN_CHUNK - 1) / SCAN_CHUNK;
  scan_a<<<nblk, 256, 0, stream>>>(cnt, off, bsum, NR);
  scan_b<<<1, 256, 0, stream>>>(bsum, nblk);
  scan_c<<<(NR + 255) / 256, 256, 0, stream>>>(off, bsum, NR);
  hipMemcpyAsync(cur, off, (size_t)NR * sizeof(int), hipMemcpyDeviceToDevice, stream);
  fill_k<<<(E + 255) / 256, 256, 0, stream>>>(esrc, edst, etyp, cur, eidx, E);

  // ---- f16 conversions ----
  convx_k<<<(N * DD / 4 + 255) / 256, 256, 0, stream>>>(x, xh, N * DD / 4);
  convw_k<<<(DD * KK + 255) / 256, 256, 0, stream>>>(W1s, W1r, WT1);
  convw_k<<<(DD * KK + 255) / 256, 256, 0, stream>>>(W2s, W2r, WT2);

  // ---- sim preprocessing (independent of RGCN) ----
  hipMemsetAsync(maskf, 0, (size_t)KP * sizeof(float), stream);
  maskset_k<<<(ND + 255) / 256, 256, 0, stream>>>(mri, maskf, ND);
  convsim_k<<<ND, 256, 0, stream>>>(sim, mri, maskf, simh, rs, ND);

  // ---- fused RGCN layers (16 rows/block, wave-split K, no K-loop barriers) ----
  rgcn_fused<true, true><<<(N + 15) / 16, 256, 0, stream>>>(
      xh, off, eidx, WT1, h1h, N, E);
  rgcn_fused<false, false><<<(N + 15) / 16, 256, 0, stream>>>(
      h1h, off, eidx, WT2, out, N, E);

  // ---- similarity diffusion ----
  hipMemsetAsync(hbs, 0, (size_t)KP * DD * sizeof(_Float16), stream);
  gather2_k<<<(ND * 32 + 255) / 256, 256, 0, stream>>>(out, bli, mri, hbp, hbs, ND);
  dim3 tgrid(KP / 64, DD / 64);
  transpose_k<<<tgrid, 256, 0, stream>>>(hbs, hbsT);
  dim3 sgrid((ND + 63) / 64, KSPLIT);
  sim_mfma<<<sgrid, 256, 0, stream>>>(simh, hbsT, hs_part, ND);
  reduce_k<<<(ND * DD / 4 + 255) / 256, 256, 0, stream>>>(hs_part, hs, ND * DD / 4);
  final_k<<<(ND * 32 + 255) / 256, 256, 0, stream>>>(hs, hbp, rs, bli, deg, out, ND);
}

// Round 7
// 343.276 us; speedup vs baseline: 1.2315x; 1.2315x over previous
//
#include <hip/hip_runtime.h>
#include <hip/hip_bf16.h>

#define DD 128
#define RR 8
#define KK 1152      // RGCN composite K = 128 + 8*128
#define SCAN_CHUNK 2048
#define KSPLIT 8
#define KP 4096      // padded sim K

typedef _Float16 h8 __attribute__((ext_vector_type(8)));
typedef _Float16 h4 __attribute__((ext_vector_type(4)));
typedef float f4 __attribute__((ext_vector_type(4)));

__device__ __forceinline__ void gload16(const _Float16* g, _Float16* l) {
  __builtin_amdgcn_global_load_lds(
      (const __attribute__((address_space(1))) void*)g,
      (__attribute__((address_space(3))) void*)l, 16, 0, 0);
}

// ---------------- count edges per (dst, rel) and in-degree ----------------
__global__ __launch_bounds__(256) void count_k(const int* __restrict__ edst,
    const int* __restrict__ etyp, int* __restrict__ cnt, int* __restrict__ deg, int E) {
  int i = blockIdx.x * 256 + threadIdx.x;
  if (i < E) {
    int d = edst[i];
    atomicAdd(&cnt[d * RR + etyp[i]], 1);
    atomicAdd(&deg[d], 1);
  }
}

// ---------------- 3-phase exclusive scan of cnt -> off ----------------
__global__ __launch_bounds__(256) void scan_a(const int* __restrict__ cnt,
    int* __restrict__ off, int* __restrict__ bsum, int n) {
  __shared__ int red[256];
  int base = blockIdx.x * SCAN_CHUNK + threadIdx.x * 8;
  int v[8];
  int s = 0;
#pragma unroll
  for (int i = 0; i < 8; ++i) {
    int idx = base + i;
    v[i] = s;
    s += (idx < n) ? cnt[idx] : 0;
  }
  red[threadIdx.x] = s;
  __syncthreads();
  for (int o = 1; o < 256; o <<= 1) {
    int t = (threadIdx.x >= o) ? red[threadIdx.x - o] : 0;
    __syncthreads();
    red[threadIdx.x] += t;
    __syncthreads();
  }
  int pre = (threadIdx.x > 0) ? red[threadIdx.x - 1] : 0;
#pragma unroll
  for (int i = 0; i < 8; ++i) {
    int idx = base + i;
    if (idx < n) off[idx] = v[i] + pre;
  }
  if (threadIdx.x == 255) bsum[blockIdx.x] = red[255];
}

__global__ void scan_b(int* __restrict__ bsum, int nb) {
  if (threadIdx.x == 0) {
    int s = 0;
    for (int i = 0; i < nb; ++i) { int t = bsum[i]; bsum[i] = s; s += t; }
  }
}

__global__ __launch_bounds__(256) void scan_c(int* __restrict__ off,
    const int* __restrict__ bsum, int n) {
  int i = blockIdx.x * 256 + threadIdx.x;
  if (i < n) off[i] += bsum[i >> 11];
}

// ---------------- fill CSR ----------------
__global__ __launch_bounds__(256) void fill_k(const int* __restrict__ esrc,
    const int* __restrict__ edst, const int* __restrict__ etyp,
    int* __restrict__ cur, int* __restrict__ eidx, int E) {
  int e = blockIdx.x * 256 + threadIdx.x;
  if (e < E) {
    int seg = edst[e] * RR + etyp[e];
    int p = atomicAdd(&cur[seg], 1);
    eidx[p] = esrc[e];
  }
}

// ---------------- fp32 -> f16 convert of x ----------------
__global__ __launch_bounds__(256) void convx_k(const float* __restrict__ x,
    _Float16* __restrict__ xh, int n4) {
  int i = blockIdx.x * 256 + threadIdx.x;
  if (i < n4) {
    float4 v = *(const float4*)(x + (size_t)i * 4);
    h4 o = {(_Float16)v.x, (_Float16)v.y, (_Float16)v.z, (_Float16)v.w};
    *(h4*)(xh + (size_t)i * 4) = o;
  }
}

// ---------------- build transposed f16 weights WT[n][k] ----------------
__global__ __launch_bounds__(256) void convw_k(const float* __restrict__ Ws,
    const float* __restrict__ Wr, _Float16* __restrict__ WT) {
  int gid = blockIdx.x * 256 + threadIdx.x;
  if (gid < DD * KK) {
    int n = gid / KK, k = gid % KK;
    float v = (k < DD) ? Ws[(size_t)k * DD + n] : Wr[(size_t)(k - DD) * DD + n];
    WT[gid] = (_Float16)v;
  }
}

// ---------------- aggregation body: 4-deep predicated pipeline, nt store ----
__device__ __forceinline__ void agg_body(const _Float16* __restrict__ h,
    const int* __restrict__ off, const int* __restrict__ eidx,
    _Float16* __restrict__ msg, int nseg, int E, int gid) {
  int seg = gid >> 5, q = gid & 31;
  if (seg >= nseg) return;
  int b = off[seg];
  int e = (seg + 1 < nseg) ? off[seg + 1] : E;
  int n = e - b;
  float a0 = 0.f, a1 = 0.f, a2 = 0.f, a3 = 0.f;
  if (n > 0) {
    int e1 = e - 1;
    // 4 independent index loads, then 4 independent gathers (breaks the
    // eidx->h dependent chain that serialized the old per-edge loop)
    int s0 = eidx[b];
    int s1 = eidx[min(b + 1, e1)];
    int s2 = eidx[min(b + 2, e1)];
    int s3 = eidx[min(b + 3, e1)];
    h4 v0 = *(const h4*)(h + (size_t)s0 * DD + q * 4);
    h4 v1 = *(const h4*)(h + (size_t)s1 * DD + q * 4);
    h4 v2 = *(const h4*)(h + (size_t)s2 * DD + q * 4);
    h4 v3 = *(const h4*)(h + (size_t)s3 * DD + q * 4);
    a0 = (float)v0[0]; a1 = (float)v0[1]; a2 = (float)v0[2]; a3 = (float)v0[3];
    if (n > 1) { a0 += (float)v1[0]; a1 += (float)v1[1]; a2 += (float)v1[2]; a3 += (float)v1[3]; }
    if (n > 2) { a0 += (float)v2[0]; a1 += (float)v2[1]; a2 += (float)v2[2]; a3 += (float)v2[3]; }
    if (n > 3) { a0 += (float)v3[0]; a1 += (float)v3[1]; a2 += (float)v3[2]; a3 += (float)v3[3]; }
    for (int i = b + 4; i < e; ++i) {  // rare tail (P(n>4) ~ 5%)
      int s = eidx[i];
      h4 v = *(const h4*)(h + (size_t)s * DD + q * 4);
      a0 += (float)v[0]; a1 += (float)v[1]; a2 += (float)v[2]; a3 += (float)v[3];
    }
  }
  float ic = (n > 0) ? 1.0f / (float)n : 0.0f;
  h4 o = {(_Float16)(a0 * ic), (_Float16)(a1 * ic),
          (_Float16)(a2 * ic), (_Float16)(a3 * ic)};
  union { h4 v; unsigned long long u; } cv; cv.v = o;
  // non-temporal: keep the 82MB msg stream from thrashing L2
  __builtin_nontemporal_store(cv.u,
      (unsigned long long*)(msg + (size_t)seg * DD + q * 4));
}

__global__ __launch_bounds__(256) void agg_k(const _Float16* __restrict__ h,
    const int* __restrict__ off, const int* __restrict__ eidx,
    _Float16* __restrict__ msg, int nseg, int E) {
  agg_body(h, off, eidx, msg, nseg, E, blockIdx.x * 256 + threadIdx.x);
}

// ---------------- sim row convert + fused rowsum (body) ----------------
__device__ __forceinline__ void convsim_body(const float* __restrict__ sim,
    const int* __restrict__ mri, const float* __restrict__ maskf,
    _Float16* __restrict__ simh, float* __restrict__ rs, int nd, int i,
    float* red) {
  const float* row = sim + (size_t)mri[i] * nd;
  float acc = 0.f;
  for (int c4 = threadIdx.x; c4 < KP / 4; c4 += 256) {
    int c = c4 * 4;
    float4 v = make_float4(0.f, 0.f, 0.f, 0.f);
    if (c < nd) {
      v = *(const float4*)(row + c);
      float4 mk = *(const float4*)(maskf + c);
      acc += v.x * mk.x + v.y * mk.y + v.z * mk.z + v.w * mk.w;
    }
    h4 o = {(_Float16)v.x, (_Float16)v.y, (_Float16)v.z, (_Float16)v.w};
    *(h4*)(simh + (size_t)i * KP + c) = o;
  }
  red[threadIdx.x] = acc;
  __syncthreads();
  for (int o = 128; o > 0; o >>= 1) {
    if (threadIdx.x < o) red[threadIdx.x] += red[threadIdx.x + o];
    __syncthreads();
  }
  if (threadIdx.x == 0) rs[i] = red[0] + 1e-9f;
}

// ---------------- co-scheduled: convsim (blocks 0..nd) + layer-1 agg ----------
__global__ __launch_bounds__(256) void agg1_convsim_k(
    const _Float16* __restrict__ h, const int* __restrict__ off,
    const int* __restrict__ eidx, _Float16* __restrict__ msg, int nseg, int E,
    const float* __restrict__ sim, const int* __restrict__ mri,
    const float* __restrict__ maskf, _Float16* __restrict__ simh,
    float* __restrict__ rs, int nd) {
  __shared__ float red[256];
  if ((int)blockIdx.x < nd) {
    convsim_body(sim, mri, maskf, simh, rs, nd, blockIdx.x, red);
  } else {
    agg_body(h, off, eidx, msg, nseg, E,
             (blockIdx.x - nd) * 256 + threadIdx.x);
  }
}

// ---------------- MFMA RGCN GEMM: out = [xh | msg] @ WT^T ----------------
// 64x128 tile, BK=64, 4 waves of 32x64, double-buffered LDS, global_load_lds
// staging (linear LDS dest, inverse-XOR-swizzled global source, XOR on read).
template <bool RELU, bool F16OUT>
__global__ __launch_bounds__(256) void rgcn_mfma(const _Float16* __restrict__ xh,
    const _Float16* __restrict__ msg, const _Float16* __restrict__ WT,
    void* __restrict__ outv, int nN) {
  __shared__ _Float16 Ab[2][64 * 64];
  __shared__ _Float16 Bb[2][128 * 64];
  const int t = threadIdx.x;
  const int lane = t & 63, w = t >> 6;
  const int row0 = blockIdx.x * 64;
  const int wm = w >> 1, wn = w & 1;
  const int lr = lane & 15, lg = lane >> 4;

  f4 acc[2][4];
#pragma unroll
  for (int mi = 0; mi < 2; ++mi)
#pragma unroll
    for (int ni = 0; ni < 4; ++ni) acc[mi][ni] = (f4){0.f, 0.f, 0.f, 0.f};

  const _Float16* pxh[2];
  const _Float16* pmsg[2];
  int ldsA[2];
#pragma unroll
  for (int j = 0; j < 2; ++j) {
    int q = j * 256 + w * 64 + lane;
    int row = q >> 3;
    int gck = (q & 7) ^ (row & 7);
    int m = row0 + row; if (m >= nN) m = nN - 1;
    pxh[j] = xh + (size_t)m * DD + gck * 8;
    pmsg[j] = msg + (size_t)m * (RR * DD) + gck * 8;
    ldsA[j] = (j * 256 + w * 64) * 8;
  }
  const _Float16* pB[4];
  int ldsB[4];
#pragma unroll
  for (int i = 0; i < 4; ++i) {
    int q = i * 256 + w * 64 + lane;
    int n = q >> 3;
    int gck = (q & 7) ^ (n & 7);
    pB[i] = WT + (size_t)n * KK + gck * 8;
    ldsB[i] = (i * 256 + w * 64) * 8;
  }

  const int nsteps = KK / 64;  // 18
#pragma unroll
  for (int j = 0; j < 2; ++j) gload16(pxh[j], &Ab[0][ldsA[j]]);
#pragma unroll
  for (int i = 0; i < 4; ++i) gload16(pB[i], &Bb[0][ldsB[i]]);
  asm volatile("s_waitcnt vmcnt(0)" ::: "memory");
  __syncthreads();

  for (int ts = 0; ts < nsteps; ++ts) {
    const int cur = ts & 1;
    if (ts + 1 < nsteps) {
      const int kk = (ts + 1) * 64;
      const int nxt = cur ^ 1;
      if (kk < DD) {
#pragma unroll
        for (int j = 0; j < 2; ++j) gload16(pxh[j] + kk, &Ab[nxt][ldsA[j]]);
      } else {
#pragma unroll
        for (int j = 0; j < 2; ++j) gload16(pmsg[j] + (kk - DD), &Ab[nxt][ldsA[j]]);
      }
#pragma unroll
      for (int i = 0; i < 4; ++i) gload16(pB[i] + kk, &Bb[nxt][ldsB[i]]);
    }
#pragma unroll
    for (int s = 0; s < 2; ++s) {
      h8 af[2], bf[4];
#pragma unroll
      for (int mi = 0; mi < 2; ++mi) {
        int r = wm * 32 + mi * 16 + lr;
        af[mi] = *(const h8*)&Ab[cur][r * 64 + (((s * 4 + lg) ^ (r & 7)) << 3)];
      }
#pragma unroll
      for (int ni = 0; ni < 4; ++ni) {
        int n = wn * 64 + ni * 16 + lr;
        bf[ni] = *(const h8*)&Bb[cur][n * 64 + (((s * 4 + lg) ^ (n & 7)) << 3)];
      }
#pragma unroll
      for (int mi = 0; mi < 2; ++mi)
#pragma unroll
        for (int ni = 0; ni < 4; ++ni)
          acc[mi][ni] = __builtin_amdgcn_mfma_f32_16x16x32_f16(
              af[mi], bf[ni], acc[mi][ni], 0, 0, 0);
    }
    asm volatile("s_waitcnt vmcnt(0)" ::: "memory");
    __syncthreads();
  }

#pragma unroll
  for (int mi = 0; mi < 2; ++mi) {
#pragma unroll
    for (int j = 0; j < 4; ++j) {
      int row = row0 + wm * 32 + mi * 16 + lg * 4 + j;
      if (row < nN) {
#pragma unroll
        for (int ni = 0; ni < 4; ++ni) {
          int col = wn * 64 + ni * 16 + lr;
          float v = acc[mi][ni][j];
          if (RELU) v = fmaxf(v, 0.f);
          if (F16OUT)
            ((_Float16*)outv)[(size_t)row * DD + col] = (_Float16)v;
          else
            ((float*)outv)[(size_t)row * DD + col] = v;
        }
      }
    }
  }
}

// ---------------- maskf scatter: maskf[mri[i]] = 1 ----------------
__global__ __launch_bounds__(256) void maskset_k(const int* __restrict__ mri,
    float* __restrict__ maskf, int nd) {
  int i = blockIdx.x * 256 + threadIdx.x;
  if (i < nd) maskf[mri[i]] = 1.0f;
}

// ---------------- gather disease rows (fp32 hbp) + scatter f16 into hbs ----------------
__global__ __launch_bounds__(256) void gather2_k(const float* __restrict__ h2,
    const int* __restrict__ bli, const int* __restrict__ mri,
    float* __restrict__ hbp, _Float16* __restrict__ hbs, int nd) {
  int gid = blockIdx.x * 256 + threadIdx.x;
  int i = gid >> 5, q = gid & 31;
  if (i < nd) {
    float4 v = *(const float4*)(h2 + (size_t)bli[i] * DD + q * 4);
    *(float4*)(hbp + (size_t)i * DD + q * 4) = v;
    h4 o = {(_Float16)v.x, (_Float16)v.y, (_Float16)v.z, (_Float16)v.w};
    *(h4*)(hbs + (size_t)mri[i] * DD + q * 4) = o;
  }
}

// ---------------- transpose hbs[KP][128] -> hbsT[128][KP] ----------------
__global__ __launch_bounds__(256) void transpose_k(const _Float16* __restrict__ hbs,
    _Float16* __restrict__ hbsT) {
  __shared__ _Float16 tile[64][72];
  int r0 = blockIdx.x * 64, c0 = blockIdx.y * 64;
  int t = threadIdx.x;
  int r = t >> 2, cs = (t & 3) * 16;
  *(h8*)&tile[r][cs]     = *(const h8*)(hbs + (size_t)(r0 + r) * DD + c0 + cs);
  *(h8*)&tile[r][cs + 8] = *(const h8*)(hbs + (size_t)(r0 + r) * DD + c0 + cs + 8);
  __syncthreads();
  int n = t >> 2, rs2 = (t & 3) * 16;
  h8 o0, o1;
#pragma unroll
  for (int j = 0; j < 8; ++j) {
    o0[j] = tile[rs2 + j][n];
    o1[j] = tile[rs2 + 8 + j][n];
  }
  *(h8*)(hbsT + (size_t)(c0 + n) * KP + r0 + rs2)     = o0;
  *(h8*)(hbsT + (size_t)(c0 + n) * KP + r0 + rs2 + 8) = o1;
}

// ---------------- sim MFMA GEMM: hs_part[ky] = simh[:, kchunk] @ hbsT^T ----------------
__global__ __launch_bounds__(256) void sim_mfma(const _Float16* __restrict__ simh,
    const _Float16* __restrict__ hbsT, float* __restrict__ hs_part, int nd) {
  __shared__ _Float16 Ab[2][64 * 64];
  __shared__ _Float16 Bb[2][128 * 64];
  const int t = threadIdx.x;
  const int lane = t & 63, w = t >> 6;
  const int row0 = blockIdx.x * 64;
  const int kb0 = blockIdx.y * (KP / KSPLIT);
  const int wm = w >> 1, wn = w & 1;
  const int lr = lane & 15, lg = lane >> 4;

  f4 acc[2][4];
#pragma unroll
  for (int mi = 0; mi < 2; ++mi)
#pragma unroll
    for (int ni = 0; ni < 4; ++ni) acc[mi][ni] = (f4){0.f, 0.f, 0.f, 0.f};

  const _Float16* pA[2];
  int ldsA[2];
#pragma unroll
  for (int j = 0; j < 2; ++j) {
    int q = j * 256 + w * 64 + lane;
    int row = q >> 3;
    int gck = (q & 7) ^ (row & 7);
    int m = row0 + row; if (m >= nd) m = nd - 1;
    pA[j] = simh + (size_t)m * KP + kb0 + gck * 8;
    ldsA[j] = (j * 256 + w * 64) * 8;
  }
  const _Float16* pB[4];
  int ldsB[4];
#pragma unroll
  for (int i = 0; i < 4; ++i) {
    int q = i * 256 + w * 64 + lane;
    int n = q >> 3;
    int gck = (q & 7) ^ (n & 7);
    pB[i] = hbsT + (size_t)n * KP + kb0 + gck * 8;
    ldsB[i] = (i * 256 + w * 64) * 8;
  }

  const int nsteps = (KP / KSPLIT) / 64;  // 8
#pragma unroll
  for (int j = 0; j < 2; ++j) gload16(pA[j], &Ab[0][ldsA[j]]);
#pragma unroll
  for (int i = 0; i < 4; ++i) gload16(pB[i], &Bb[0][ldsB[i]]);
  asm volatile("s_waitcnt vmcnt(0)" ::: "memory");
  __syncthreads();

  for (int ts = 0; ts < nsteps; ++ts) {
    const int cur = ts & 1;
    if (ts + 1 < nsteps) {
      const int kk = (ts + 1) * 64;
      const int nxt = cur ^ 1;
#pragma unroll
      for (int j = 0; j < 2; ++j) gload16(pA[j] + kk, &Ab[nxt][ldsA[j]]);
#pragma unroll
      for (int i = 0; i < 4; ++i) gload16(pB[i] + kk, &Bb[nxt][ldsB[i]]);
    }
#pragma unroll
    for (int s = 0; s < 2; ++s) {
      h8 af[2], bf[4];
#pragma unroll
      for (int mi = 0; mi < 2; ++mi) {
        int r = wm * 32 + mi * 16 + lr;
        af[mi] = *(const h8*)&Ab[cur][r * 64 + (((s * 4 + lg) ^ (r & 7)) << 3)];
      }
#pragma unroll
      for (int ni = 0; ni < 4; ++ni) {
        int n = wn * 64 + ni * 16 + lr;
        bf[ni] = *(const h8*)&Bb[cur][n * 64 + (((s * 4 + lg) ^ (n & 7)) << 3)];
      }
#pragma unroll
      for (int mi = 0; mi < 2; ++mi)
#pragma unroll
        for (int ni = 0; ni < 4; ++ni)
          acc[mi][ni] = __builtin_amdgcn_mfma_f32_16x16x32_f16(
              af[mi], bf[ni], acc[mi][ni], 0, 0, 0);
    }
    asm volatile("s_waitcnt vmcnt(0)" ::: "memory");
    __syncthreads();
  }

  float* dst = hs_part + (size_t)blockIdx.y * nd * DD;
#pragma unroll
  for (int mi = 0; mi < 2; ++mi) {
#pragma unroll
    for (int j = 0; j < 4; ++j) {
      int row = row0 + wm * 32 + mi * 16 + lg * 4 + j;
      if (row < nd) {
#pragma unroll
        for (int ni = 0; ni < 4; ++ni) {
          int col = wn * 64 + ni * 16 + lr;
          dst[(size_t)row * DD + col] = acc[mi][ni][j];
        }
      }
    }
  }
}

__global__ __launch_bounds__(256) void reduce_k(const float* __restrict__ part,
    float* __restrict__ hs, int n) {
  int i = blockIdx.x * 256 + threadIdx.x;
  if (i < n) {
    float4 s = make_float4(0.f, 0.f, 0.f, 0.f);
#pragma unroll
    for (int p = 0; p < KSPLIT; ++p) {
      float4 v = *(const float4*)(part + (size_t)p * n * 4 + i * 4);
      s.x += v.x; s.y += v.y; s.z += v.z; s.w += v.w;
    }
    *(float4*)(hs + (size_t)i * 4) = s;
  }
}

// ---------------- final blend into d_out at disease rows ----------------
__global__ __launch_bounds__(256) void final_k(const float* __restrict__ hs,
    const float* __restrict__ hbp, const float* __restrict__ rs,
    const int* __restrict__ bli, const int* __restrict__ deg,
    float* __restrict__ out, int nd) {
  int gid = blockIdx.x * 256 + threadIdx.x;
  int i = gid >> 5, q = gid & 31;
  if (i < nd) {
    int g = bli[i];
    float cg = 0.7f * expf(-0.7f * (float)deg[g]) + 0.2f;
    float inv = 1.0f / rs[i];
    float4 s = *(const float4*)(hs + (size_t)i * DD + q * 4);
    float4 b = *(const float4*)(hbp + (size_t)i * DD + q * 4);
    float4 o;
    o.x = cg * (s.x * inv) + (1.f - cg) * b.x;
    o.y = cg * (s.y * inv) + (1.f - cg) * b.y;
    o.z = cg * (s.z * inv) + (1.f - cg) * b.z;
    o.w = cg * (s.w * inv) + (1.f - cg) * b.w;
    *(float4*)(out + (size_t)g * DD + q * 4) = o;
  }
}

extern "C" void kernel_launch(void* const* d_in, const int* in_sizes, int n_in,
                              void* d_out, int out_size, void* d_ws, size_t ws_size,
                              hipStream_t stream) {
  const float* x   = (const float*)d_in[0];
  const float* sim = (const float*)d_in[1];
  const float* W1s = (const float*)d_in[2];
  const float* W1r = (const float*)d_in[3];
  const float* W2s = (const float*)d_in[4];
  const float* W2r = (const float*)d_in[5];
  const int* esrc  = (const int*)d_in[6];
  const int* edst  = (const int*)d_in[7];
  const int* etyp  = (const int*)d_in[8];
  const int* bli   = (const int*)d_in[9];
  const int* mri   = (const int*)d_in[10];
  const int N  = in_sizes[0] / DD;
  const int E  = in_sizes[6];
  const int ND = in_sizes[9];
  const int NR = N * RR;
  float* out = (float*)d_out;

  // workspace carve-up (~165 MB)
  char* w = (char*)d_ws;
  _Float16* msg  = (_Float16*)w; w += (size_t)NR * DD * sizeof(_Float16);   // 82 MB
  _Float16* xh   = (_Float16*)w; w += (size_t)N * DD * sizeof(_Float16);
  _Float16* h1h  = (_Float16*)w; w += (size_t)N * DD * sizeof(_Float16);
  _Float16* WT1  = (_Float16*)w; w += (size_t)DD * KK * sizeof(_Float16);
  _Float16* WT2  = (_Float16*)w; w += (size_t)DD * KK * sizeof(_Float16);
  _Float16* simh = (_Float16*)w; w += (size_t)ND * KP * sizeof(_Float16);
  _Float16* hbs  = (_Float16*)w; w += (size_t)KP * DD * sizeof(_Float16);
  _Float16* hbsT = (_Float16*)w; w += (size_t)DD * KP * sizeof(_Float16);
  float* hs_part = (float*)w; w += (size_t)KSPLIT * ND * DD * sizeof(float);
  float* hbp   = (float*)w; w += (size_t)ND * DD * sizeof(float);
  float* hs    = (float*)w; w += (size_t)ND * DD * sizeof(float);
  float* maskf = (float*)w; w += (size_t)KP * sizeof(float);
  int* cnt  = (int*)w; w += (size_t)NR * sizeof(int);
  int* deg  = (int*)w; w += (size_t)N * sizeof(int);
  int* off  = (int*)w; w += (size_t)NR * sizeof(int);
  int* cur  = (int*)w; w += (size_t)NR * sizeof(int);
  int* eidx = (int*)w; w += (size_t)E * sizeof(int);
  int* bsum = (int*)w; w += 1024 * sizeof(int);
  float* rs = (float*)w; w += (size_t)ND * sizeof(float);

  // ---- CSR build ----
  hipMemsetAsync(cnt, 0, (size_t)(NR + N) * sizeof(int), stream);
  count_k<<<(E + 255) / 256, 256, 0, stream>>>(edst, etyp, cnt, deg, E);
  int nblk = (NR + SCAN_CHUNK - 1) / SCAN_CHUNK;
  scan_a<<<nblk, 256, 0, stream>>>(cnt, off, bsum, NR);
  scan_b<<<1, 256, 0, stream>>>(bsum, nblk);
  scan_c<<<(NR + 255) / 256, 256, 0, stream>>>(off, bsum, NR);
  hipMemcpyAsync(cur, off, (size_t)NR * sizeof(int), hipMemcpyDeviceToDevice, stream);
  fill_k<<<(E + 255) / 256, 256, 0, stream>>>(esrc, edst, etyp, cur, eidx, E);

  // ---- f16 conversions + sim mask prep + hbs clear (all independent) ----
  convx_k<<<(N * DD / 4 + 255) / 256, 256, 0, stream>>>(x, xh, N * DD / 4);
  convw_k<<<(DD * KK + 255) / 256, 256, 0, stream>>>(W1s, W1r, WT1);
  convw_k<<<(DD * KK + 255) / 256, 256, 0, stream>>>(W2s, W2r, WT2);
  hipMemsetAsync(maskf, 0, (size_t)KP * sizeof(float), stream);
  maskset_k<<<(ND + 255) / 256, 256, 0, stream>>>(mri, maskf, ND);
  hipMemsetAsync(hbs, 0, (size_t)KP * DD * sizeof(_Float16), stream);

  // ---- layer 1 aggregation co-scheduled with convsim ----
  int aggBlk = (NR * 32 + 255) / 256;
  agg1_convsim_k<<<ND + aggBlk, 256, 0, stream>>>(
      xh, off, eidx, msg, NR, E, sim, mri, maskf, simh, rs, ND);
  rgcn_mfma<true, true><<<(N + 63) / 64, 256, 0, stream>>>(xh, msg, WT1, h1h, N);

  // ---- layer 2 ----
  agg_k<<<aggBlk, 256, 0, stream>>>(h1h, off, eidx, msg, NR, E);
  rgcn_mfma<false, false><<<(N + 63) / 64, 256, 0, stream>>>(h1h, msg, WT2, out, N);

  // ---- similarity diffusion ----
  gather2_k<<<(ND * 32 + 255) / 256, 256, 0, stream>>>(out, bli, mri, hbp, hbs, ND);
  dim3 tgrid(KP / 64, DD / 64);
  transpose_k<<<tgrid, 256, 0, stream>>>(hbs, hbsT);
  dim3 sgrid((ND + 63) / 64, KSPLIT);
  sim_mfma<<<sgrid, 256, 0, stream>>>(simh, hbsT, hs_part, ND);
  reduce_k<<<(ND * DD / 4 + 255) / 256, 256, 0, stream>>>(hs_part, hs, ND * DD / 4);
  final_k<<<(ND * 32 + 255) / 256, 256, 0, stream>>>(hs, hbp, rs, bli, deg, out, ND);
}